// Round 5
// baseline (1036.446 us; speedup 1.0000x reference)
//
#include <hip/hip_runtime.h>
#include <math.h>

// ---------------- problem constants ----------------
#define BB 16
#define CIN 15
#define HW 384
#define XPL 147456             // 384*384
#define PH 96
#define GW 192
#define WPAD 390               // padded spatial (3 halo each side)
#define XP_IMG 2433600         // 390*390*16 elems per image
#define YP 98                  // padded Y1 spatial
#define Y1IPL (98*98*64)       // 614656 elems per image
#define OUT_ELEMS (BB*6*PH*PH)

// ws byte offsets (peak 60,441,600 <= proven available 77,594,624)
#define OFF_WG   0             // frag-major [28][4][512] bf16 (BN-folded)  114,688 B
#define OFF_WE1  114688        // [3][28][4][512] bf16                      344,064 B
#define OFF_WH   458752        // [3][18][24][512] bf16                   1,327,104 B
#define OFF_GSH  1785856       // fp32 [64]
#define OFF_FEAT 1786112       // fp32 [16][64]
#define OFF_IDX  1790208       // int  [16]
#define OFF_Y1   1835008       // bf16 [16][98][98][64] = 19,668,992 B (doubles as gating Cbuf chunks)
#define OFF_XPAD 21504000      // bf16 [8][390][390][16] = 38,937,600 B (half batch)

typedef __attribute__((ext_vector_type(8))) short short8;
typedef __attribute__((ext_vector_type(4))) float floatx4;
typedef __attribute__((ext_vector_type(4))) unsigned int uintx4;
typedef __attribute__((ext_vector_type(2))) unsigned int uintx2;

__device__ __forceinline__ unsigned bf16rne(float f) {
  unsigned u = __float_as_uint(f);
  unsigned r = ((u >> 16) & 1u) + 0x7FFFu;
  return (u + r) >> 16;
}
__device__ __forceinline__ float bf2f(unsigned short s) {
  return __uint_as_float(((unsigned)s) << 16);
}

// ---------------- K0: weight prep (fragment-major) ----------------
// Wg/We1: chunk c = ky*4+kxc (28); idx = ((c*4+mt)*512 + lane*8 + j);
//   oc = mt*16+(lane&15); kx = kxc*2+(q>>1); ic = (q&1)*8+j  (kx==7 or ic==15 -> 0).
// Wh: idx = ((kk*2+ih)*24 + mt)*512 + lane*8 + j; oc = mt*16+(lane&15); ic = ih*32+q*8+j.
__global__ __launch_bounds__(256) void k_prep(
    const float* __restrict__ g_conv_w, const float* __restrict__ e_conv1_w,
    const float* __restrict__ e_head_w1,
    const float* __restrict__ gamma, const float* __restrict__ var,
    const float* __restrict__ beta,  const float* __restrict__ mean,
    unsigned char* __restrict__ wsb)
{
  int i = blockIdx.x * 256 + threadIdx.x;
  unsigned short* Wg  = (unsigned short*)(wsb + OFF_WG);
  unsigned short* We1 = (unsigned short*)(wsb + OFF_WE1);
  unsigned short* Wh  = (unsigned short*)(wsb + OFF_WH);
  float* gsh = (float*)(wsb + OFF_GSH);
  if (i < 57344) {
    int j = i & 7, lane = (i >> 3) & 63, mt = (i >> 9) & 3, c = i >> 11;
    int ky = c >> 2, kxc = c & 3, q = lane >> 4;
    int oc = mt * 16 + (lane & 15);
    int kx = kxc * 2 + (q >> 1), ic = (q & 1) * 8 + j;
    float v = 0.f;
    if (kx < 7 && ic < 15) v = g_conv_w[oc * 735 + ic * 49 + ky * 7 + kx];
    float inv = gamma[oc] * rsqrtf(var[oc] + 1e-5f);
    Wg[i] = (unsigned short)bf16rne(v * inv);
  } else if (i < 229376) {
    int r = i - 57344;
    int e = r / 57344, r2 = r % 57344;
    int j = r2 & 7, lane = (r2 >> 3) & 63, mt = (r2 >> 9) & 3, c = r2 >> 11;
    int ky = c >> 2, kxc = c & 3, q = lane >> 4;
    int oc = mt * 16 + (lane & 15);
    int kx = kxc * 2 + (q >> 1), ic = (q & 1) * 8 + j;
    float v = 0.f;
    if (kx < 7 && ic < 15) v = e_conv1_w[(e * 64 + oc) * 735 + ic * 49 + ky * 7 + kx];
    We1[r] = (unsigned short)bf16rne(v);
  } else if (i < 892928) {
    int r = i - 229376;
    int e = r / 221184, r2 = r % 221184;
    int j = r2 & 7, lane = (r2 >> 3) & 63, mtc = r2 >> 9;
    int mt = mtc % 24, chunk = mtc / 24;
    int kk = chunk >> 1, ih = chunk & 1;
    int oc = mt * 16 + (lane & 15), q = lane >> 4;
    int ic = ih * 32 + q * 8 + j;
    Wh[r] = (unsigned short)bf16rne(e_head_w1[((e * 384 + oc) * 64 + ic) * 9 + kk]);
  } else if (i < 892992) {
    int oc = i - 892928;
    float inv = gamma[oc] * rsqrtf(var[oc] + 1e-5f);
    gsh[oc] = beta[oc] - mean[oc] * inv;
  }
}

// ---------------- K1: x -> NHWC-16 bf16 with 3-px zero halo (half batch) ----------------
// layout [img][row390][col390][16ch]; ch15 = 0. grid (390, 8) block 256.
__global__ __launch_bounds__(256) void k_xpad(
    const float* __restrict__ x, unsigned short* __restrict__ xp, int b0)
{
  const int row = blockIdx.x, img = blockIdx.y, b = b0 + img;
  const int iy = row - 3;
  const bool rok = (iy >= 0) && (iy < HW);
  unsigned short* orow = xp + ((size_t)img * WPAD + row) * WPAD * 16;
  const float* xb = x + (size_t)b * CIN * XPL + (size_t)iy * HW;
  for (int col = threadIdx.x; col < WPAD; col += 256) {
    int ix = col - 3;
    bool ok = rok && (ix >= 0) && (ix < HW);
    uintx4 w0, w1;
    unsigned v[16];
#pragma unroll
    for (int ic = 0; ic < 15; ++ic)
      v[ic] = ok ? bf16rne(xb[(size_t)ic * XPL + ix]) : 0u;
    v[15] = 0u;
    w0.x = v[0] | (v[1] << 16);  w0.y = v[2] | (v[3] << 16);
    w0.z = v[4] | (v[5] << 16);  w0.w = v[6] | (v[7] << 16);
    w1.x = v[8] | (v[9] << 16);  w1.y = v[10] | (v[11] << 16);
    w1.z = v[12] | (v[13] << 16); w1.w = v[14];
    uintx4* op = (uintx4*)(orow + col * 16);
    op[0] = w0; op[1] = w1;
  }
}

// ---------------- MFMA 7x7 conv from NHWC-16 xpad (S=2 gating / S=4 expert) ----------------
// Block: 16x16 out tile, 4 waves; wave w rows w*4..w*4+3 (nt), all 64 oc (4 mt).
// A: coalesced b128 frag-major weights. B: ONE aligned b128 per frag from xpad.
template<int S, int OW, bool EXP>
__global__ __launch_bounds__(256) void k_conv7n(
    const unsigned short* __restrict__ xp, const unsigned short* __restrict__ Wp,
    const float* __restrict__ biasp, const int* __restrict__ idxb,
    unsigned short* __restrict__ Obuf, int imgoff, int b0)
{
  const int t = threadIdx.x, w = t >> 6, lane = t & 63, q = lane >> 4, ln = lane & 15;
  const int z = blockIdx.z;
  const int img = imgoff + z;            // xpad image index (within half)
  const int b = b0 + imgoff + z;         // global batch index
  const int e = EXP ? idxb[b] : 0;
  const unsigned short* W = Wp + e * 57344;
  const float* bs = EXP ? (biasp + e * 64) : biasp;
  const int px0 = blockIdx.x * 16, py0 = blockIdx.y * 16;
  const int px = px0 + ln;

  const unsigned short* bp[4];
#pragma unroll
  for (int nt = 0; nt < 4; ++nt) {
    int row = S * (py0 + w * 4 + nt);
    bp[nt] = xp + ((size_t)img * WPAD + row) * WPAD * 16
                + ((size_t)S * px + (q >> 1)) * 16 + (q & 1) * 8;
  }

  floatx4 acc[4][4];
#pragma unroll
  for (int mt = 0; mt < 4; ++mt)
#pragma unroll
    for (int nt = 0; nt < 4; ++nt) acc[mt][nt] = 0.f;

#pragma unroll 2
  for (int ky = 0; ky < 7; ++ky) {
#pragma unroll
    for (int kxc = 0; kxc < 4; ++kxc) {
      const int c = ky * 4 + kxc;
      short8 af[4];
#pragma unroll
      for (int mt = 0; mt < 4; ++mt)
        af[mt] = *(const short8*)(W + ((c * 4 + mt) << 9) + lane * 8);
      const int koff = (ky * WPAD + 2 * kxc) * 16;
      short8 bf[4];
#pragma unroll
      for (int nt = 0; nt < 4; ++nt) {
        union { uintx4 u; short8 s; } cv;
        cv.u = *(const uintx4*)(bp[nt] + koff);
        bf[nt] = cv.s;
      }
#pragma unroll
      for (int mt = 0; mt < 4; ++mt)
#pragma unroll
        for (int nt = 0; nt < 4; ++nt)
          acc[mt][nt] = __builtin_amdgcn_mfma_f32_16x16x32_bf16(af[mt], bf[nt], acc[mt][nt], 0, 0, 0);
    }
  }

#pragma unroll
  for (int nt = 0; nt < 4; ++nt) {
    int py = py0 + w * 4 + nt;
    size_t rowo;
    if (EXP)   // padded Y1 NHWC [b][py+1][px+1][64]
      rowo = (((size_t)b * YP + py + 1) * YP + px + 1) * 64;
    else       // chunk-local Cbuf NHWC [z][py][px][64]
      rowo = (((size_t)z * OW + py) * OW + px) * 64;
#pragma unroll
    for (int mt = 0; mt < 4; ++mt) {
      int ocb = mt * 16 + q * 4;
      float v0 = fmaxf(acc[mt][nt][0] + bs[ocb + 0], 0.f);
      float v1 = fmaxf(acc[mt][nt][1] + bs[ocb + 1], 0.f);
      float v2 = fmaxf(acc[mt][nt][2] + bs[ocb + 2], 0.f);
      float v3 = fmaxf(acc[mt][nt][3] + bs[ocb + 3], 0.f);
      uintx2 pr;
      pr.x = (bf16rne(v1) << 16) | bf16rne(v0);
      pr.y = (bf16rne(v3) << 16) | bf16rne(v2);
      *(uintx2*)(Obuf + rowo + ocb) = pr;
    }
  }
}

// ---------------- pool(3x3 s2 p1) + mean partial (4-image chunk) ----------------
__global__ __launch_bounds__(256) void k_pool(const unsigned short* __restrict__ Cb,
                                              float* __restrict__ feat, int bg0)
{
  const int py = blockIdx.x, z = blockIdx.y;
  const int t = threadIdx.x, oc = t & 63, strip = t >> 6;
  const unsigned short* base = Cb + (size_t)z * GW * GW * 64 + oc;
  float sum = 0.f;
  for (int px = strip * 24; px < strip * 24 + 24; ++px) {
    float m = 0.f;
#pragma unroll
    for (int dy = 0; dy < 3; ++dy) {
      int row = 2 * py - 1 + dy;
      if (row < 0 || row >= GW) continue;
#pragma unroll
      for (int dx = 0; dx < 3; ++dx) {
        int col = 2 * px - 1 + dx;
        if (col < 0 || col >= GW) continue;
        m = fmaxf(m, bf2f(base[((size_t)row * GW + col) * 64]));
      }
    }
    sum += m;
  }
  __shared__ float red[4][64];
  red[strip][oc] = sum;
  __syncthreads();
  if (t < 64) {
    float s = red[0][oc] + red[1][oc] + red[2][oc] + red[3][oc];
    atomicAdd(&feat[(bg0 + z) * 64 + oc], s);
  }
}

// ---------------- FC + argmax + aux (feat holds SUMS) ----------------
__global__ __launch_bounds__(64) void k_gate_fc(
    const float* __restrict__ feat, const float* __restrict__ fcw,
    const float* __restrict__ fcb, int* __restrict__ idxb,
    float* __restrict__ out_aux)
{
  __shared__ float sm[16][3];
  __shared__ int sidx[16];
  int t = threadIdx.x;
  if (t < 16) {
    float l[3];
#pragma unroll
    for (int e = 0; e < 3; ++e) {
      float s = fcb[e];
      for (int c = 0; c < 64; ++c)
        s = fmaf(feat[t * 64 + c] * (1.f / 9216.f), fcw[e * 64 + c], s);
      l[e] = s;
    }
    int best = 0; float bv = l[0];
    if (l[1] > bv) { bv = l[1]; best = 1; }
    if (l[2] > bv) { bv = l[2]; best = 2; }
    sidx[t] = best; idxb[t] = best;
    float mx = fmaxf(l[0], fmaxf(l[1], l[2]));
    float e0 = expf(l[0] - mx), e1 = expf(l[1] - mx), e2 = expf(l[2] - mx);
    float d = e0 + e1 + e2;
    sm[t][0] = e0 / d; sm[t][1] = e1 / d; sm[t][2] = e2 / d;
  }
  __syncthreads();
  if (t == 0) {
    float aux = 0.f;
    for (int e = 0; e < 3; ++e) {
      float cnt = 0.f, pr = 0.f;
      for (int b = 0; b < 16; ++b) { cnt += (sidx[b] == e) ? 1.f : 0.f; pr += sm[b][e]; }
      aux += (cnt / 16.f) * (pr / 16.f);
    }
    *out_aux = 0.01f * aux * 3.f;
  }
}

// ---------------- head: 3x3 64->384 MFMA (frag-major A) + fused grouped 1x1 ----------------
__global__ __launch_bounds__(256) void k_headm(
    const unsigned short* __restrict__ Y1, const unsigned short* __restrict__ Whp,
    const float* __restrict__ b1, const float* __restrict__ w2,
    const float* __restrict__ b2, const int* __restrict__ idxb,
    float* __restrict__ out)
{
  const int t = threadIdx.x, w = t >> 6, lane = t & 63, q = lane >> 4, ln = lane & 15;
  const int b = blockIdx.z, px0 = blockIdx.x * 16, py0 = blockIdx.y * 4;
  const int e = idxb[b];
  const unsigned short* W = Whp + e * 221184;
  const int px = px0 + ln;

  int bbase[4];
#pragma unroll
  for (int nt = 0; nt < 4; ++nt)
    bbase[nt] = ((b * YP + py0 + nt) * YP + px) * 64 + q * 8;

  floatx4 acc[6][4];
#pragma unroll
  for (int mt = 0; mt < 6; ++mt)
#pragma unroll
    for (int nt = 0; nt < 4; ++nt) acc[mt][nt] = 0.f;

#pragma unroll
  for (int kk = 0; kk < 9; ++kk) {
    const int ky = kk / 3, kx = kk % 3;
#pragma unroll
    for (int ih = 0; ih < 2; ++ih) {
      const int stepc = (ky * YP + kx) * 64 + ih * 32;
      short8 bf[4];
#pragma unroll
      for (int nt = 0; nt < 4; ++nt) {
        union { uintx4 u; short8 s; } cv;
        cv.u = *(const uintx4*)(Y1 + bbase[nt] + stepc);
        bf[nt] = cv.s;
      }
      const int cbase = ((kk * 2 + ih) * 24 + w * 6) << 9;
#pragma unroll
      for (int mt = 0; mt < 6; ++mt) {
        short8 af = *(const short8*)(W + cbase + (mt << 9) + lane * 8);
#pragma unroll
        for (int nt = 0; nt < 4; ++nt)
          acc[mt][nt] = __builtin_amdgcn_mfma_f32_16x16x32_bf16(af, bf[nt], acc[mt][nt], 0, 0, 0);
      }
    }
  }

  __shared__ float sred[4][4][16][6];
#pragma unroll
  for (int nt = 0; nt < 4; ++nt) {
    float part[6] = {0.f, 0.f, 0.f, 0.f, 0.f, 0.f};
#pragma unroll
    for (int mt = 0; mt < 6; ++mt) {
      int ocb = w * 96 + mt * 16 + q * 4;
#pragma unroll
      for (int r = 0; r < 4; ++r) {
        int oc = ocb + r;
        float y = fmaxf(acc[mt][nt][r] + b1[e * 384 + oc], 0.f);
        int g = oc >> 7, kb = oc & 127;
        part[2 * g]     += y * w2[(e * 6 + 2 * g) * 128 + kb];
        part[2 * g + 1] += y * w2[(e * 6 + 2 * g + 1) * 128 + kb];
      }
    }
#pragma unroll
    for (int c = 0; c < 6; ++c) {
      part[c] += __shfl_down(part[c], 32);
      part[c] += __shfl_down(part[c], 16);
    }
    if (q == 0) {
#pragma unroll
      for (int c = 0; c < 6; ++c) sred[nt][w][ln][c] = part[c];
    }
  }
  __syncthreads();
  for (int i = t; i < 384; i += 256) {
    int pix = i / 6, c = i % 6;
    int nt = pix >> 4, pl = pix & 15;
    float s = sred[nt][0][pl][c] + sred[nt][1][pl][c] + sred[nt][2][pl][c] +
              sred[nt][3][pl][c] + b2[e * 6 + c];
    out[(((size_t)(b * 6 + c)) * PH + (py0 + nt)) * PH + (px0 + pl)] = s;
  }
}

// ---------------- launch ----------------
extern "C" void kernel_launch(void* const* d_in, const int* in_sizes, int n_in,
                              void* d_out, int out_size, void* d_ws, size_t ws_size,
                              hipStream_t stream)
{
  const float* x         = (const float*)d_in[0];
  const float* g_fc_w    = (const float*)d_in[6];
  const float* g_fc_b    = (const float*)d_in[7];
  const float* e_conv1_b = (const float*)d_in[9];
  const float* e_head_b1 = (const float*)d_in[11];
  const float* e_head_w2 = (const float*)d_in[12];
  const float* e_head_b2 = (const float*)d_in[13];

  unsigned char* wsb = (unsigned char*)d_ws;
  unsigned short* Wg  = (unsigned short*)(wsb + OFF_WG);
  unsigned short* We1 = (unsigned short*)(wsb + OFF_WE1);
  unsigned short* Wh  = (unsigned short*)(wsb + OFF_WH);
  float* gsh  = (float*)(wsb + OFF_GSH);
  float* feat = (float*)(wsb + OFF_FEAT);
  int*   idxb = (int*)(wsb + OFF_IDX);
  unsigned short* Y1   = (unsigned short*)(wsb + OFF_Y1);   // also gating Cbuf chunks
  unsigned short* xpad = (unsigned short*)(wsb + OFF_XPAD);

  float* out = (float*)d_out;
  float* out_aux = out + OUT_ELEMS;

  hipMemsetAsync(feat, 0, 16 * 64 * sizeof(float), stream);
  hipLaunchKernelGGL(k_prep, dim3(3489), dim3(256), 0, stream,
                     (const float*)d_in[1], (const float*)d_in[8], (const float*)d_in[10],
                     (const float*)d_in[2], (const float*)d_in[5],
                     (const float*)d_in[3], (const float*)d_in[4], wsb);

  // gating: half 0
  hipLaunchKernelGGL(k_xpad, dim3(WPAD, 8), dim3(256), 0, stream, x, xpad, 0);
  hipLaunchKernelGGL((k_conv7n<2, GW, false>), dim3(12, 12, 4), dim3(256), 0, stream,
                     xpad, Wg, gsh, idxb, Y1, 0, 0);
  hipLaunchKernelGGL(k_pool, dim3(96, 4), dim3(256), 0, stream, Y1, feat, 0);
  hipLaunchKernelGGL((k_conv7n<2, GW, false>), dim3(12, 12, 4), dim3(256), 0, stream,
                     xpad, Wg, gsh, idxb, Y1, 4, 0);
  hipLaunchKernelGGL(k_pool, dim3(96, 4), dim3(256), 0, stream, Y1, feat, 4);
  // gating: half 1
  hipLaunchKernelGGL(k_xpad, dim3(WPAD, 8), dim3(256), 0, stream, x, xpad, 8);
  hipLaunchKernelGGL((k_conv7n<2, GW, false>), dim3(12, 12, 4), dim3(256), 0, stream,
                     xpad, Wg, gsh, idxb, Y1, 0, 8);
  hipLaunchKernelGGL(k_pool, dim3(96, 4), dim3(256), 0, stream, Y1, feat, 8);
  hipLaunchKernelGGL((k_conv7n<2, GW, false>), dim3(12, 12, 4), dim3(256), 0, stream,
                     xpad, Wg, gsh, idxb, Y1, 4, 8);
  hipLaunchKernelGGL(k_pool, dim3(96, 4), dim3(256), 0, stream, Y1, feat, 12);

  hipLaunchKernelGGL(k_gate_fc, dim3(1), dim3(64), 0, stream,
                     feat, g_fc_w, g_fc_b, idxb, out_aux);

  // expert conv1 -> padded Y1 (zero halo); xpad currently holds half 1
  hipMemsetAsync(Y1, 0, (size_t)BB * Y1IPL * 2, stream);
  hipLaunchKernelGGL((k_conv7n<4, PH, true>), dim3(6, 6, 8), dim3(256), 0, stream,
                     xpad, We1, e_conv1_b, idxb, Y1, 0, 8);
  hipLaunchKernelGGL(k_xpad, dim3(WPAD, 8), dim3(256), 0, stream, x, xpad, 0);
  hipLaunchKernelGGL((k_conv7n<4, PH, true>), dim3(6, 6, 8), dim3(256), 0, stream,
                     xpad, We1, e_conv1_b, idxb, Y1, 0, 0);

  hipLaunchKernelGGL(k_headm, dim3(6, 24, 16), dim3(256), 0, stream,
                     Y1, Wh, e_head_b1, e_head_w2, e_head_b2, idxb, out);
}

// Round 6
// 699.375 us; speedup vs baseline: 1.4820x; 1.4820x over previous
//
#include <hip/hip_runtime.h>
#include <math.h>

// ---------------- problem constants ----------------
#define BB 16
#define CIN 15
#define HW 384
#define XPL 147456             // 384*384
#define NX 35389440            // 16*15*384*384
#define PH 96
#define GW 192
#define YP 98                  // padded Y1 spatial
#define Y1IPL (98*98*64)       // 614656 elems per image
#define OUT_ELEMS (BB*6*PH*PH)

// ws byte offsets (end = 77,594,624 == proven available, round-4 layout)
#define OFF_WG   0             // frag-major [30][4][512] bf16 (BN-folded)
#define OFF_WE1  122880        // frag-major [3][30][4][512] bf16
#define OFF_WH   491520        // frag-major [3][18][24][512] bf16
#define OFF_GSH  1818624       // fp32 [64]
#define OFF_FEAT 1818880       // fp32 [16][64]
#define OFF_IDX  1822976       // int  [16]
#define OFF_CBUF 2097152       // bf16 [16][192][192][64] = 75,497,472 B; Y1 overlays

typedef __attribute__((ext_vector_type(8))) short short8;
typedef __attribute__((ext_vector_type(4))) float floatx4;
typedef __attribute__((ext_vector_type(4))) unsigned int uintx4;
typedef __attribute__((ext_vector_type(2))) unsigned int uintx2;

__device__ __forceinline__ unsigned bf16rne(float f) {
  unsigned u = __float_as_uint(f);
  unsigned r = ((u >> 16) & 1u) + 0x7FFFu;
  return (u + r) >> 16;
}
__device__ __forceinline__ float bf2f(unsigned short s) {
  return __uint_as_float(((unsigned)s) << 16);
}

// ---------------- K0: weight prep (fragment-major) — round-4 verbatim ----------------
__global__ __launch_bounds__(256) void k_prep(
    const float* __restrict__ g_conv_w, const float* __restrict__ e_conv1_w,
    const float* __restrict__ e_head_w1,
    const float* __restrict__ gamma, const float* __restrict__ var,
    const float* __restrict__ beta,  const float* __restrict__ mean,
    unsigned char* __restrict__ wsb)
{
  int i = blockIdx.x * 256 + threadIdx.x;
  unsigned short* Wg  = (unsigned short*)(wsb + OFF_WG);
  unsigned short* We1 = (unsigned short*)(wsb + OFF_WE1);
  unsigned short* Wh  = (unsigned short*)(wsb + OFF_WH);
  float* gsh = (float*)(wsb + OFF_GSH);
  if (i < 61440) {
    int j = i & 7, lane = (i >> 3) & 63, mtc = i >> 9;
    int mt = mtc & 3, c = mtc >> 2, ic = c >> 1, h = c & 1;
    int oc = mt * 16 + (lane & 15), q = lane >> 4;
    int ky = 4 * h + q, kx = j;
    float v = 0.f;
    if (ky < 7 && kx < 7) v = g_conv_w[oc * 735 + ic * 49 + ky * 7 + kx];
    float inv = gamma[oc] * rsqrtf(var[oc] + 1e-5f);
    Wg[i] = (unsigned short)bf16rne(v * inv);
  } else if (i < 245760) {
    int r = i - 61440;
    int e = r / 61440, r2 = r % 61440;
    int j = r2 & 7, lane = (r2 >> 3) & 63, mtc = r2 >> 9;
    int mt = mtc & 3, c = mtc >> 2, ic = c >> 1, h = c & 1;
    int oc = mt * 16 + (lane & 15), q = lane >> 4;
    int ky = 4 * h + q, kx = j;
    float v = 0.f;
    if (ky < 7 && kx < 7) v = e_conv1_w[(e * 64 + oc) * 735 + ic * 49 + ky * 7 + kx];
    We1[r] = (unsigned short)bf16rne(v);
  } else if (i < 909312) {
    int r = i - 245760;
    int e = r / 221184, r2 = r % 221184;
    int j = r2 & 7, lane = (r2 >> 3) & 63, mtc = r2 >> 9;
    int mt = mtc % 24, chunk = mtc / 24;
    int kk = chunk >> 1, ih = chunk & 1;
    int oc = mt * 16 + (lane & 15), q = lane >> 4;
    int ic = ih * 32 + q * 8 + j;
    Wh[r] = (unsigned short)bf16rne(e_head_w1[((e * 384 + oc) * 64 + ic) * 9 + kk]);
  } else if (i < 909376) {
    int oc = i - 909312;
    float inv = gamma[oc] * rsqrtf(var[oc] + 1e-5f);
    gsh[oc] = beta[oc] - mean[oc] * inv;
  }
}

// ---------------- K1: gating conv 7x7 s2 — LDS tile, BATCHED staging ----------------
// grid (12,12,16) block 256 (4 waves). 16x16 out tile; wave w rows w*4..w*4+3.
// LDS [15 ic][38 rows][20 dw] (dw 19 = pad). 3 staging passes x 15 loads in flight.
__global__ __launch_bounds__(256) void k_gconv(
    const float* __restrict__ x, const unsigned short* __restrict__ Wg,
    const float* __restrict__ gsh, unsigned short* __restrict__ Cbuf)
{
  const int t = threadIdx.x, w = t >> 6, lane = t & 63, q = lane >> 4, ln = lane & 15;
  const int px0 = blockIdx.x * 16, py0 = blockIdx.y * 16, b = blockIdx.z;
  const int iy0 = 2 * py0 - 3, ix0 = 2 * px0 - 3;

  __shared__ unsigned tilU[11400];   // 45,600 B

  const float* xb = x + (size_t)b * CIN * XPL;
  // staging: 10830 real dwords; 3 passes of up to 15 batched loads/thread
  for (int base = 0; base < 10830; base += 3840) {
    float v0[15], v1[15];
#pragma unroll
    for (int r = 0; r < 15; ++r) {
      int p = base + r * 256 + t;
      v0[r] = 0.f; v1[r] = 0.f;
      if (p < 10830) {
        int ic = p / 722;
        int r2 = p - ic * 722;
        int rr = r2 / 19, cp = r2 - rr * 19;
        int iy = iy0 + rr;
        int c0 = ix0 + 2 * cp;
        if (iy >= 0 && iy < HW) {
          const float* xr = xb + (size_t)ic * XPL + (size_t)iy * HW;
          if (c0 >= 0 && c0 < HW) v0[r] = xr[c0];
          if (c0 + 1 >= 0 && c0 + 1 < HW) v1[r] = xr[c0 + 1];
        }
      }
    }
#pragma unroll
    for (int r = 0; r < 15; ++r) {
      int p = base + r * 256 + t;
      if (p < 10830) {
        int ic = p / 722;
        int r2 = p - ic * 722;
        int rr = r2 / 19, cp = r2 - rr * 19;
        tilU[ic * 760 + rr * 20 + cp] = bf16rne(v0[r]) | (bf16rne(v1[r]) << 16);
      }
    }
  }
  __syncthreads();

  floatx4 acc[4][4];
#pragma unroll
  for (int mt = 0; mt < 4; ++mt)
#pragma unroll
    for (int nt = 0; nt < 4; ++nt) acc[mt][nt] = 0.f;

#pragma unroll 3
  for (int ic = 0; ic < CIN; ++ic) {
#pragma unroll
    for (int h = 0; h < 2; ++h) {
      short8 af[4];
#pragma unroll
      for (int mt = 0; mt < 4; ++mt)
        af[mt] = *(const short8*)(Wg + (((ic * 2 + h) * 4 + mt) << 9) + lane * 8);
      short8 bf[4];
#pragma unroll
      for (int nt = 0; nt < 4; ++nt) {
        int row = 2 * (w * 4 + nt) + 4 * h + q;
        int bd = ic * 760 + row * 20 + ln;
        union { unsigned u[4]; short8 s; } cv;
        cv.u[0] = tilU[bd]; cv.u[1] = tilU[bd + 1];
        cv.u[2] = tilU[bd + 2]; cv.u[3] = tilU[bd + 3];
        bf[nt] = cv.s;
      }
#pragma unroll
      for (int mt = 0; mt < 4; ++mt)
#pragma unroll
        for (int nt = 0; nt < 4; ++nt)
          acc[mt][nt] = __builtin_amdgcn_mfma_f32_16x16x32_bf16(af[mt], bf[nt], acc[mt][nt], 0, 0, 0);
    }
  }

#pragma unroll
  for (int nt = 0; nt < 4; ++nt) {
    int py = py0 + w * 4 + nt, px = px0 + ln;
    size_t rowo = (((size_t)b * GW + py) * GW + px) * 64;
#pragma unroll
    for (int mt = 0; mt < 4; ++mt) {
      int ocb = mt * 16 + q * 4;
      float v0 = fmaxf(acc[mt][nt][0] + gsh[ocb + 0], 0.f);
      float v1 = fmaxf(acc[mt][nt][1] + gsh[ocb + 1], 0.f);
      float v2 = fmaxf(acc[mt][nt][2] + gsh[ocb + 2], 0.f);
      float v3 = fmaxf(acc[mt][nt][3] + gsh[ocb + 3], 0.f);
      uintx2 pr;
      pr.x = (bf16rne(v1) << 16) | bf16rne(v0);
      pr.y = (bf16rne(v3) << 16) | bf16rne(v2);
      *(uintx2*)(Cbuf + rowo + ocb) = pr;
    }
  }
}

// ---------------- pool(3x3 s2 p1) + mean partial (full batch) ----------------
__global__ __launch_bounds__(256) void k_pool(const unsigned short* __restrict__ Cb,
                                              float* __restrict__ feat)
{
  const int py = blockIdx.x, b = blockIdx.y;
  const int t = threadIdx.x, oc = t & 63, strip = t >> 6;
  const unsigned short* base = Cb + (size_t)b * GW * GW * 64 + oc;
  float sum = 0.f;
  for (int px = strip * 24; px < strip * 24 + 24; ++px) {
    float m = 0.f;
#pragma unroll
    for (int dy = 0; dy < 3; ++dy) {
      int row = 2 * py - 1 + dy;
      if (row < 0 || row >= GW) continue;
#pragma unroll
      for (int dx = 0; dx < 3; ++dx) {
        int col = 2 * px - 1 + dx;
        if (col < 0 || col >= GW) continue;
        m = fmaxf(m, bf2f(base[((size_t)row * GW + col) * 64]));
      }
    }
    sum += m;
  }
  __shared__ float red[4][64];
  red[strip][oc] = sum;
  __syncthreads();
  if (t < 64) {
    float s = red[0][oc] + red[1][oc] + red[2][oc] + red[3][oc];
    atomicAdd(&feat[b * 64 + oc], s);
  }
}

// ---------------- FC + argmax + aux (feat holds SUMS) ----------------
__global__ __launch_bounds__(64) void k_gate_fc(
    const float* __restrict__ feat, const float* __restrict__ fcw,
    const float* __restrict__ fcb, int* __restrict__ idxb,
    float* __restrict__ out_aux)
{
  __shared__ float sm[16][3];
  __shared__ int sidx[16];
  int t = threadIdx.x;
  if (t < 16) {
    float l[3];
#pragma unroll
    for (int e = 0; e < 3; ++e) {
      float s = fcb[e];
      for (int c = 0; c < 64; ++c)
        s = fmaf(feat[t * 64 + c] * (1.f / 9216.f), fcw[e * 64 + c], s);
      l[e] = s;
    }
    int best = 0; float bv = l[0];
    if (l[1] > bv) { bv = l[1]; best = 1; }
    if (l[2] > bv) { bv = l[2]; best = 2; }
    sidx[t] = best; idxb[t] = best;
    float mx = fmaxf(l[0], fmaxf(l[1], l[2]));
    float e0 = expf(l[0] - mx), e1 = expf(l[1] - mx), e2 = expf(l[2] - mx);
    float d = e0 + e1 + e2;
    sm[t][0] = e0 / d; sm[t][1] = e1 / d; sm[t][2] = e2 / d;
  }
  __syncthreads();
  if (t == 0) {
    float aux = 0.f;
    for (int e = 0; e < 3; ++e) {
      float cnt = 0.f, pr = 0.f;
      for (int b = 0; b < 16; ++b) { cnt += (sidx[b] == e) ? 1.f : 0.f; pr += sm[b][e]; }
      aux += (cnt / 16.f) * (pr / 16.f);
    }
    *out_aux = 0.01f * aux * 3.f;
  }
}

// ---------------- K4: expert conv1 7x7 s4 — round-4 verbatim ----------------
__global__ __launch_bounds__(256) void k_econv(
    const float* __restrict__ x, const unsigned short* __restrict__ We1,
    const float* __restrict__ biasp, const int* __restrict__ idxb,
    unsigned short* __restrict__ Y1)
{
  const int t = threadIdx.x, w = t >> 6, lane = t & 63, q = lane >> 4, ln = lane & 15;
  const int b = blockIdx.z;
  const int e = idxb[b];
  const unsigned short* W = We1 + e * 61440;
  const float* bs = biasp + e * 64;
  const int px0 = blockIdx.x * 16, py0 = blockIdx.y * 16;
  const int px = px0 + ln;

  const int c0 = 4 * px - 3;
  const int acol = c0 - 1;
  unsigned pm[4];
#pragma unroll
  for (int j = 0; j < 4; ++j) {
    int t0 = 2 * j, t1 = 2 * j + 1;
    unsigned m0 = (c0 + t0 >= 0 && c0 + t0 < HW) ? 0x0000FFFFu : 0u;
    unsigned m1 = (c0 + t1 >= 0 && c0 + t1 < HW) ? 0xFFFF0000u : 0u;
    pm[j] = m0 | m1;
  }

  int syq[4];
#pragma unroll
  for (int nt = 0; nt < 4; ++nt) syq[nt] = 4 * (py0 + w * 4 + nt) + q - 3;
  const int xbase = b * CIN * XPL;

  floatx4 acc[4][4];
#pragma unroll
  for (int mt = 0; mt < 4; ++mt)
#pragma unroll
    for (int nt = 0; nt < 4; ++nt) acc[mt][nt] = 0.f;

#pragma unroll 3
  for (int ic = 0; ic < CIN; ++ic) {
    const int icb = xbase + ic * XPL;
#pragma unroll
    for (int h = 0; h < 2; ++h) {
      short8 af[4];
#pragma unroll
      for (int mt = 0; mt < 4; ++mt)
        af[mt] = *(const short8*)(W + (((ic * 2 + h) * 4 + mt) << 9) + lane * 8);
      short8 bf[4];
#pragma unroll
      for (int nt = 0; nt < 4; ++nt) {
        int iy = syq[nt] + 4 * h;
        bool rv = (iy >= 0) && (iy < HW) && ((4 * h + q) < 7);
        int a0 = icb + iy * HW + acol;
        a0 = max(a0, 0); a0 = min(a0, NX - 12);
        const float* fp = x + a0;
        floatx4 fA = *(const floatx4*)(fp);
        floatx4 fB = *(const floatx4*)(fp + 4);
        floatx4 fC = *(const floatx4*)(fp + 8);
        float g[8];
        g[0] = fA.y; g[1] = fA.z; g[2] = fA.w; g[3] = fB.x;
        g[4] = fB.y; g[5] = fB.z; g[6] = fB.w; g[7] = fC.x;
        union { unsigned u[4]; short8 s; } cv;
#pragma unroll
        for (int j = 0; j < 4; ++j) {
          unsigned p = __builtin_amdgcn_perm(__float_as_uint(g[2 * j + 1]),
                                             __float_as_uint(g[2 * j]), 0x07060302u);
          p &= pm[j];
          cv.u[j] = rv ? p : 0u;
        }
        bf[nt] = cv.s;
      }
#pragma unroll
      for (int mt = 0; mt < 4; ++mt)
#pragma unroll
        for (int nt = 0; nt < 4; ++nt)
          acc[mt][nt] = __builtin_amdgcn_mfma_f32_16x16x32_bf16(af[mt], bf[nt], acc[mt][nt], 0, 0, 0);
    }
  }

#pragma unroll
  for (int nt = 0; nt < 4; ++nt) {
    int py = py0 + w * 4 + nt;
    size_t rowo = (((size_t)b * YP + py + 1) * YP + px + 1) * 64;
#pragma unroll
    for (int mt = 0; mt < 4; ++mt) {
      int ocb = mt * 16 + q * 4;
      float v0 = fmaxf(acc[mt][nt][0] + bs[ocb + 0], 0.f);
      float v1 = fmaxf(acc[mt][nt][1] + bs[ocb + 1], 0.f);
      float v2 = fmaxf(acc[mt][nt][2] + bs[ocb + 2], 0.f);
      float v3 = fmaxf(acc[mt][nt][3] + bs[ocb + 3], 0.f);
      uintx2 pr;
      pr.x = (bf16rne(v1) << 16) | bf16rne(v0);
      pr.y = (bf16rne(v3) << 16) | bf16rne(v2);
      *(uintx2*)(Y1 + rowo + ocb) = pr;
    }
  }
}

// ---------------- head: 3x3 64->384 MFMA — LDS-staged B patch, N=96 ----------------
// grid (6,16,16): 16 px x 6 py tile; wave w = 96 oc (6 mt). One barrier.
__global__ __launch_bounds__(256) void k_headm(
    const unsigned short* __restrict__ Y1, const unsigned short* __restrict__ Whp,
    const float* __restrict__ b1, const float* __restrict__ w2,
    const float* __restrict__ b2, const int* __restrict__ idxb,
    float* __restrict__ out)
{
  const int t = threadIdx.x, w = t >> 6, lane = t & 63, q = lane >> 4, ln = lane & 15;
  const int b = blockIdx.z, px0 = blockIdx.x * 16, py0 = blockIdx.y * 6;
  const int e = idxb[b];
  const unsigned short* W = Whp + e * 221184;

  __shared__ unsigned short patch[8 * 18 * 72];   // 20,736 B; rows py0-1..+6, cols px0-1..+16
  __shared__ float sred[6][4][16][6];             // 9,216 B

  // stage 8*18*8 = 1152 b128 segs, batched (5 in flight)
  {
    uintx4 vv[5];
#pragma unroll
    for (int r = 0; r < 5; ++r) {
      int i = r * 256 + t;
      if (i < 1152) {
        int row = i / 144, rem = i % 144, col = rem >> 3, s = rem & 7;
        vv[r] = *(const uintx4*)(Y1 + (((size_t)b * YP + py0 + row) * YP + (px0 + col)) * 64 + s * 8);
      }
    }
#pragma unroll
    for (int r = 0; r < 5; ++r) {
      int i = r * 256 + t;
      if (i < 1152) {
        int row = i / 144, rem = i % 144, col = rem >> 3, s = rem & 7;
        *(uintx4*)(patch + (row * 18 + col) * 72 + s * 8) = vv[r];
      }
    }
  }
  __syncthreads();

  floatx4 acc[6][6];
#pragma unroll
  for (int mt = 0; mt < 6; ++mt)
#pragma unroll
    for (int nt = 0; nt < 6; ++nt) acc[mt][nt] = 0.f;

#pragma unroll
  for (int kk = 0; kk < 9; ++kk) {
    const int ky = kk / 3, kx = kk % 3;
#pragma unroll
    for (int ih = 0; ih < 2; ++ih) {
      short8 bf[6];
#pragma unroll
      for (int nt = 0; nt < 6; ++nt) {
        int off = ((nt + ky) * 18 + (ln + kx)) * 72 + ih * 32 + q * 8;
        bf[nt] = *(const short8*)(patch + off);
      }
      const int cbase = ((kk * 2 + ih) * 24 + w * 6) << 9;
#pragma unroll
      for (int mt = 0; mt < 6; ++mt) {
        short8 af = *(const short8*)(W + cbase + (mt << 9) + lane * 8);
#pragma unroll
        for (int nt = 0; nt < 6; ++nt)
          acc[mt][nt] = __builtin_amdgcn_mfma_f32_16x16x32_bf16(af, bf[nt], acc[mt][nt], 0, 0, 0);
      }
    }
  }

#pragma unroll
  for (int nt = 0; nt < 6; ++nt) {
    float part[6] = {0.f, 0.f, 0.f, 0.f, 0.f, 0.f};
#pragma unroll
    for (int mt = 0; mt < 6; ++mt) {
      int ocb = w * 96 + mt * 16 + q * 4;
#pragma unroll
      for (int r = 0; r < 4; ++r) {
        int oc = ocb + r;
        float y = fmaxf(acc[mt][nt][r] + b1[e * 384 + oc], 0.f);
        int g = oc >> 7, kb = oc & 127;
        part[2 * g]     += y * w2[(e * 6 + 2 * g) * 128 + kb];
        part[2 * g + 1] += y * w2[(e * 6 + 2 * g + 1) * 128 + kb];
      }
    }
#pragma unroll
    for (int c = 0; c < 6; ++c) {
      part[c] += __shfl_down(part[c], 32);
      part[c] += __shfl_down(part[c], 16);
    }
    if (q == 0) {
#pragma unroll
      for (int c = 0; c < 6; ++c) sred[nt][w][ln][c] = part[c];
    }
  }
  __syncthreads();
  for (int i = t; i < 576; i += 256) {
    int pix = i / 6, c = i % 6;
    int nt = pix >> 4, pl = pix & 15;
    float s = sred[nt][0][pl][c] + sred[nt][1][pl][c] + sred[nt][2][pl][c] +
              sred[nt][3][pl][c] + b2[e * 6 + c];
    out[(((size_t)(b * 6 + c)) * PH + (py0 + nt)) * PH + (px0 + pl)] = s;
  }
}

// ---------------- launch ----------------
extern "C" void kernel_launch(void* const* d_in, const int* in_sizes, int n_in,
                              void* d_out, int out_size, void* d_ws, size_t ws_size,
                              hipStream_t stream)
{
  const float* x         = (const float*)d_in[0];
  const float* g_fc_w    = (const float*)d_in[6];
  const float* g_fc_b    = (const float*)d_in[7];
  const float* e_conv1_b = (const float*)d_in[9];
  const float* e_head_b1 = (const float*)d_in[11];
  const float* e_head_w2 = (const float*)d_in[12];
  const float* e_head_b2 = (const float*)d_in[13];

  unsigned char* wsb = (unsigned char*)d_ws;
  unsigned short* Wg  = (unsigned short*)(wsb + OFF_WG);
  unsigned short* We1 = (unsigned short*)(wsb + OFF_WE1);
  unsigned short* Wh  = (unsigned short*)(wsb + OFF_WH);
  float* gsh  = (float*)(wsb + OFF_GSH);
  float* feat = (float*)(wsb + OFF_FEAT);
  int*   idxb = (int*)(wsb + OFF_IDX);
  unsigned short* Cbuf = (unsigned short*)(wsb + OFF_CBUF);
  unsigned short* Y1   = (unsigned short*)(wsb + OFF_CBUF);  // overlays Cbuf

  float* out = (float*)d_out;
  float* out_aux = out + OUT_ELEMS;

  hipMemsetAsync(feat, 0, 16 * 64 * sizeof(float), stream);
  hipLaunchKernelGGL(k_prep, dim3(3553), dim3(256), 0, stream,
                     (const float*)d_in[1], (const float*)d_in[8], (const float*)d_in[10],
                     (const float*)d_in[2], (const float*)d_in[5],
                     (const float*)d_in[3], (const float*)d_in[4], wsb);

  hipLaunchKernelGGL(k_gconv, dim3(12, 12, 16), dim3(256), 0, stream,
                     x, Wg, gsh, Cbuf);
  hipLaunchKernelGGL(k_pool, dim3(96, 16), dim3(256), 0, stream, Cbuf, feat);
  hipLaunchKernelGGL(k_gate_fc, dim3(1), dim3(64), 0, stream,
                     feat, g_fc_w, g_fc_b, idxb, out_aux);

  // Y1 overlays Cbuf (consumed by pool); zero for halo, then expert conv fills interior
  hipMemsetAsync(Y1, 0, (size_t)BB * Y1IPL * 2, stream);
  hipLaunchKernelGGL(k_econv, dim3(6, 6, 16), dim3(256), 0, stream,
                     x, We1, e_conv1_b, idxb, Y1);

  hipLaunchKernelGGL(k_headm, dim3(6, 16, 16), dim3(256), 0, stream,
                     Y1, Wh, e_head_b1, e_head_w2, e_head_b2, idxb, out);
}